// Round 17
// baseline (164.213 us; speedup 1.0000x reference)
//
#include <hip/hip_runtime.h>

// GAT layer, N=8192, IN_F=128, OUT_F=64.
//   Wh = h@W; Wh1 = Wh@a1; Wh2 = Wh@a2
//   e[i][j] = leakyrelu(Wh1[i]+Wh2[j]); p = adj>0 ? exp(e) : 0
//   out = (P @ Wh) / rowsum(P)
// Round 16: MEASUREMENT ROUND on the round-15 structure (71.2us best).
// gat_main body runs REPS=3x inside one dispatch (idempotent) so it enters
// rocprof top-5 with full counters. Verdict: hbm_gbps>=5TB/s => roofline;
// ~4TB/s + low VALU + 0 conflicts => latency still exposed; conflicts>0 =>
// fix B/P LDS layout. Revert to REPS=1 next round.

#define NN    8192
#define INF   128
#define OUTF  64
#define BM    32       // rows per block
#define RJ    256      // j per round
#define NR    (NN/RJ)  // 32 rounds
#define REPS  3        // measurement repeats (revert to 1)
#define LOG2E 1.4426950408889634f

typedef float  f32x4 __attribute__((ext_vector_type(4)));
typedef int    i32x4 __attribute__((ext_vector_type(4)));
typedef __bf16 bf16x4 __attribute__((ext_vector_type(4)));
typedef __bf16 bf16x8 __attribute__((ext_vector_type(8)));

__device__ __forceinline__ unsigned short f2bf(float x) {
    unsigned u = __builtin_bit_cast(unsigned, x);
    return (unsigned short)((u + 0x7fffu + ((u >> 16) & 1u)) >> 16);
}

// Raw barrier: own LDS ops drained (lgkmcnt(0)), VMEM left in flight.
__device__ __forceinline__ void bar_lgkm_only() {
    asm volatile("s_waitcnt lgkmcnt(0)" ::: "memory");
    __builtin_amdgcn_sched_barrier(0);
    __builtin_amdgcn_s_barrier();
    __builtin_amdgcn_sched_barrier(0);
}

// ---------------- kernel 1: Wh, scaled Wh1/Wh2, packed bf16 Wh (B-frag order)
// (byte-identical to round 6)
__global__ __launch_bounds__(512) void gat_prep(
    const float* __restrict__ h, const float* __restrict__ W,
    const float* __restrict__ a, float* __restrict__ wh1s,
    float* __restrict__ wh2s, unsigned short* __restrict__ whbp)
{
    __shared__ float sWt[64 * 132];   // W transposed [col][k], padded
    __shared__ float sWh[32][64];
    __shared__ float sH[8][128];
    __shared__ float sA[2 * OUTF];
    const int tid = threadIdx.x, lane = tid & 63, wid = tid >> 6;
    const int rb = blockIdx.x;

    for (int idx = tid; idx < INF * OUTF; idx += 512) {
        int k = idx >> 6, c = idx & 63;
        sWt[c * 132 + k] = W[idx];
    }
    if (tid < 2 * OUTF) sA[tid] = a[tid];
    __syncthreads();

    #pragma unroll
    for (int i = 0; i < 4; ++i) {
        const int row = wid * 4 + i;
        const int grow = rb * BM + row;
        sH[wid][lane]      = h[(size_t)grow * INF + lane];
        sH[wid][64 + lane] = h[(size_t)grow * INF + 64 + lane];
        float a0 = 0.f, a1 = 0.f, a2 = 0.f, a3 = 0.f;
        #pragma unroll
        for (int k = 0; k < INF; k += 4) {
            f32x4 wv = *(const f32x4*)(&sWt[lane * 132 + k]);
            f32x4 hv = *(const f32x4*)(&sH[wid][k]);
            a0 = fmaf(hv[0], wv[0], a0);
            a1 = fmaf(hv[1], wv[1], a1);
            a2 = fmaf(hv[2], wv[2], a2);
            a3 = fmaf(hv[3], wv[3], a3);
        }
        float acc = (a0 + a1) + (a2 + a3);
        float v1 = acc * sA[lane];
        float v2 = acc * sA[64 + lane];
        #pragma unroll
        for (int off = 32; off; off >>= 1) {
            v1 += __shfl_xor(v1, off);
            v2 += __shfl_xor(v2, off);
        }
        if (lane == 0) { wh1s[grow] = v1 * LOG2E; wh2s[grow] = v2 * LOG2E; }
        sWh[row][lane] = acc;
    }
    __syncthreads();

    // coalesced whbp chunk write: thread t -> shorts t*4 .. t*4+3
    {
        const int t = tid;
        const int nb  = t >> 7;
        const int lp  = (t & 127) >> 1;
        const int jj0 = (t & 1) * 4;
        const int col = nb * 16 + (lp & 15);
        const int jb  = (lp >> 4) * 8 + jj0;
        unsigned short v[4];
        #pragma unroll
        for (int q = 0; q < 4; ++q) v[q] = f2bf(sWh[jb + q][col]);
        *(uint2*)(whbp + (size_t)rb * 2048 + t * 4) = *(const uint2*)v;
    }
}

// ---------------- kernel 2: round-15 body wrapped in REPS loop
__global__ __launch_bounds__(512) void gat_main(
    const int* __restrict__ adj, const float* __restrict__ wh1s,
    const float* __restrict__ wh2s, const unsigned short* __restrict__ whbp,
    float* __restrict__ out)
{
    __shared__ __align__(16) char smem[32768 + 65536];  // 96 KB
    __shared__ float sRow[BM];

    const int tid = threadIdx.x, lane = tid & 63, wid = tid >> 6;
    const int rb = blockIdx.x;
    const int r16 = lane & 15, klo = lane >> 4;

    // phase-A role: 4 rows per wave
    const int ra0 = 4 * wid;
    const int* adjr[4];
    float wh1v[4];
    int xw[4];
    #pragma unroll
    for (int r = 0; r < 4; ++r) {
        const int grow = rb * BM + ra0 + r;
        adjr[r] = adj + (size_t)grow * NN;
        wh1v[r] = wh1s[grow];
        xw[r]   = ((ra0 + r) & 7) << 4;
    }

    // phase-B role
    const int rh = wid >> 2, js = wid & 3;
    const int rloc = rh * 16 + r16;
    const int xr = (rloc & 7) << 4;

    for (int rep = 0; rep < REPS; ++rep) {
        __syncthreads();   // protect smem reuse across reps

        f32x4 acc[4];
        #pragma unroll
        for (int nb = 0; nb < 4; ++nb) acc[nb] = (f32x4){0.f, 0.f, 0.f, 0.f};
        float rs[4] = {0.f, 0.f, 0.f, 0.f};

        struct AdjSet { i32x4 a[4]; f32x4 w; };
        AdjSet S0, S1;

        auto LOADA = [&](AdjSet& S, int rr) {
            const int jb = rr * RJ + lane * 4;
            #pragma unroll
            for (int r = 0; r < 4; ++r)
                S.a[r] = *(const i32x4*)(adjr[r] + jb);
            S.w = *(const f32x4*)(wh2s + jb);
        };

        auto PROC = [&](i32x4 ad, f32x4 w2, float w1, float& rsum) -> bf16x4 {
            bf16x4 o;
            #pragma unroll
            for (int u = 0; u < 4; ++u) {
                float tt = w1 + w2[u];
                float e  = fmaxf(tt, 0.2f * tt);             // leaky (log2 domain)
                float p  = (ad[u] > 0) ? __builtin_amdgcn_exp2f(e) : 0.f;
                rsum += p;
                o[u] = (__bf16)p;
            }
            return o;
        };

        auto STORE = [&](int rr, AdjSet& S) {   // produce P(rr) into P half rr&1
            char* Pb = smem + ((rr & 1) << 14);
            #pragma unroll
            for (int r = 0; r < 4; ++r) {
                bf16x4 p = PROC(S.a[r], S.w, wh1v[r], rs[r]);
                *(bf16x4*)(Pb + (ra0 + r) * 512 + ((lane * 8) ^ xw[r])) = p;
            }
        };

        auto STAGEB_LOAD = [&](i32x4* T, int rr) {
            const i32x4* src = (const i32x4*)(whbp +
                (size_t)rr * (RJ / 32) * 2048 + wid * 2048 + lane * 8);
            T[0] = src[0];
            T[1] = src[64];    // +512 shorts
            T[2] = src[128];
            T[3] = src[192];
        };
        auto STAGEB_WRITE = [&](const i32x4* T, int rr) {
            char* Bd = smem + 32768 + ((rr & 1) << 15) + wid * 4096 + lane * 16;
            *(i32x4*)(Bd)        = T[0];
            *(i32x4*)(Bd + 1024) = T[1];
            *(i32x4*)(Bd + 2048) = T[2];
            *(i32x4*)(Bd + 3072) = T[3];
        };

        auto PHASE = [&](int rr, AdjSet& Scons) {
            bar_lgkm_only();                 // P(rr),B(rr) visible; VMEM in flight

            const bool hasNext = (rr + 1 < NR);
            i32x4 T[4];
            if (hasNext) STAGEB_LOAD(T, rr + 1);
            if (hasNext) {
                STORE(rr + 1, Scons);
                if (rr + 3 < NR) LOADA(Scons, rr + 3);
                STAGEB_WRITE(T, rr + 1);
            }

            const char* Pb = smem + ((rr & 1) << 14);
            const char* Bb = smem + 32768 + ((rr & 1) << 15);
            #pragma unroll
            for (int kk = 0; kk < 2; ++kk) {
                bf16x8 af = *(const bf16x8*)(Pb + rloc * 512 +
                    ((js * 128 + kk * 64 + klo * 16) ^ xr));
                const char* bc = Bb + (js * 2 + kk) * 4096 + lane * 16;
                #pragma unroll
                for (int nb = 0; nb < 4; ++nb) {
                    bf16x8 bf = *(const bf16x8*)(bc + nb * 1024);
                    acc[nb] = __builtin_amdgcn_mfma_f32_16x16x32_bf16(
                        af, bf, acc[nb], 0, 0, 0);
                }
            }
        };

        // prologue: adj depth-2, P(0), B(0)
        LOADA(S0, 0);
        LOADA(S1, 1);
        {
            i32x4 T[4];
            STAGEB_LOAD(T, 0);
            STORE(0, S0);
            LOADA(S0, 2);
            STAGEB_WRITE(T, 0);
        }
        for (int rr = 0; rr < NR; rr += 2) {
            PHASE(rr, S1);
            PHASE(rr + 1, S0);
        }

        // per-row softmax denominators
        #pragma unroll
        for (int r = 0; r < 4; ++r) {
            float v = rs[r];
            #pragma unroll
            for (int off = 32; off; off >>= 1) v += __shfl_xor(v, off);
            if (lane == 0) sRow[ra0 + r] = v;
        }

        __syncthreads();   // all P reads done; safe to alias smem as sAcc

        // spill acc (C/D layout: row = klo*4 + q, col = nb*16 + r16)
        float* sAcc = (float*)smem;          // [8][1024] = 32 KB (P region)
        #pragma unroll
        for (int nb = 0; nb < 4; ++nb) {
            #pragma unroll
            for (int q = 0; q < 4; ++q) {
                int lrow = klo * 4 + q;
                sAcc[wid * 1024 + lrow * 64 + nb * 16 + r16] = acc[nb][q];
            }
        }
        __syncthreads();

        // combine the 4 j-slice waves per rowhalf, divide, write out
        for (int idx = tid; idx < BM * OUTF; idx += 512) {
            int row = idx >> 6, c = idx & 63, rhh = row >> 4;
            float s = 0.f;
            #pragma unroll
            for (int j4 = 0; j4 < 4; ++j4)
                s += sAcc[(rhh * 4 + j4) * 1024 + (row & 15) * 64 + c];
            out[(size_t)(rb * BM + row) * OUTF + c] = s / sRow[row];
        }
    }
}

extern "C" void kernel_launch(void* const* d_in, const int* in_sizes, int n_in,
                              void* d_out, int out_size, void* d_ws, size_t ws_size,
                              hipStream_t stream) {
    const float* h   = (const float*)d_in[0];
    const float* W   = (const float*)d_in[1];
    const float* a   = (const float*)d_in[2];
    const int*   adj = (const int*)d_in[3];
    float* out = (float*)d_out;

    char* ws = (char*)d_ws;
    unsigned short* whbp = (unsigned short*)ws;             // 1 MB
    float* wh1s = (float*)(ws + (1u << 20));                // 32 KB
    float* wh2s = (float*)(ws + (1u << 20) + 32768);        // 32 KB

    gat_prep<<<NN / BM, 512, 0, stream>>>(h, W, a, wh1s, wh2s, whbp);
    gat_main<<<NN / BM, 512, 0, stream>>>(adj, wh1s, wh2s, whbp, out);
}

// Round 18
// 69.141 us; speedup vs baseline: 2.3750x; 2.3750x over previous
//
#include <hip/hip_runtime.h>

// GAT layer, N=8192, IN_F=128, OUT_F=64.
//   Wh = h@W; Wh1 = Wh@a1; Wh2 = Wh@a2
//   e[i][j] = leakyrelu(Wh1[i]+Wh2[j]); p = adj>0 ? exp(e) : 0
//   out = (P @ Wh) / rowsum(P)
// Round 18: single change vs round 15 (71.2us best) — B fragments staged
// into REGISTERS one full phase ahead (2 named sets, static idx), not LDS.
// Removes the B LDS round-trip (the bulk of 590K conflict-cycles/rep and
// of the barrier's lgkm drain), LDS drops 96KB->32KB. adj stays depth-2
// counted-vmcnt; P staging via swizzled LDS unchanged.

#define NN    8192
#define INF   128
#define OUTF  64
#define BM    32       // rows per block
#define RJ    256      // j per round
#define NR    (NN/RJ)  // 32 rounds
#define LOG2E 1.4426950408889634f

typedef float  f32x4 __attribute__((ext_vector_type(4)));
typedef int    i32x4 __attribute__((ext_vector_type(4)));
typedef __bf16 bf16x4 __attribute__((ext_vector_type(4)));
typedef __bf16 bf16x8 __attribute__((ext_vector_type(8)));

__device__ __forceinline__ unsigned short f2bf(float x) {
    unsigned u = __builtin_bit_cast(unsigned, x);
    return (unsigned short)((u + 0x7fffu + ((u >> 16) & 1u)) >> 16);
}

// Raw barrier: own LDS ops drained (lgkmcnt(0)), VMEM left in flight.
__device__ __forceinline__ void bar_lgkm_only() {
    asm volatile("s_waitcnt lgkmcnt(0)" ::: "memory");
    __builtin_amdgcn_sched_barrier(0);
    __builtin_amdgcn_s_barrier();
    __builtin_amdgcn_sched_barrier(0);
}

// ---------------- kernel 1: Wh, scaled Wh1/Wh2, packed bf16 Wh (B-frag order)
// (byte-identical to round 6)
__global__ __launch_bounds__(512) void gat_prep(
    const float* __restrict__ h, const float* __restrict__ W,
    const float* __restrict__ a, float* __restrict__ wh1s,
    float* __restrict__ wh2s, unsigned short* __restrict__ whbp)
{
    __shared__ float sWt[64 * 132];   // W transposed [col][k], padded
    __shared__ float sWh[32][64];
    __shared__ float sH[8][128];
    __shared__ float sA[2 * OUTF];
    const int tid = threadIdx.x, lane = tid & 63, wid = tid >> 6;
    const int rb = blockIdx.x;

    for (int idx = tid; idx < INF * OUTF; idx += 512) {
        int k = idx >> 6, c = idx & 63;
        sWt[c * 132 + k] = W[idx];
    }
    if (tid < 2 * OUTF) sA[tid] = a[tid];
    __syncthreads();

    #pragma unroll
    for (int i = 0; i < 4; ++i) {
        const int row = wid * 4 + i;
        const int grow = rb * BM + row;
        sH[wid][lane]      = h[(size_t)grow * INF + lane];
        sH[wid][64 + lane] = h[(size_t)grow * INF + 64 + lane];
        float a0 = 0.f, a1 = 0.f, a2 = 0.f, a3 = 0.f;
        #pragma unroll
        for (int k = 0; k < INF; k += 4) {
            f32x4 wv = *(const f32x4*)(&sWt[lane * 132 + k]);
            f32x4 hv = *(const f32x4*)(&sH[wid][k]);
            a0 = fmaf(hv[0], wv[0], a0);
            a1 = fmaf(hv[1], wv[1], a1);
            a2 = fmaf(hv[2], wv[2], a2);
            a3 = fmaf(hv[3], wv[3], a3);
        }
        float acc = (a0 + a1) + (a2 + a3);
        float v1 = acc * sA[lane];
        float v2 = acc * sA[64 + lane];
        #pragma unroll
        for (int off = 32; off; off >>= 1) {
            v1 += __shfl_xor(v1, off);
            v2 += __shfl_xor(v2, off);
        }
        if (lane == 0) { wh1s[grow] = v1 * LOG2E; wh2s[grow] = v2 * LOG2E; }
        sWh[row][lane] = acc;
    }
    __syncthreads();

    // coalesced whbp chunk write: thread t -> shorts t*4 .. t*4+3
    {
        const int t = tid;
        const int nb  = t >> 7;
        const int lp  = (t & 127) >> 1;
        const int jj0 = (t & 1) * 4;
        const int col = nb * 16 + (lp & 15);
        const int jb  = (lp >> 4) * 8 + jj0;
        unsigned short v[4];
        #pragma unroll
        for (int q = 0; q < 4; ++q) v[q] = f2bf(sWh[jb + q][col]);
        *(uint2*)(whbp + (size_t)rb * 2048 + t * 4) = *(const uint2*)v;
    }
}

// ---------------- kernel 2: P via swizzled LDS, B via register double-buffer
// 256 blocks x 512 threads (8 waves). Phase A: wave w owns rows 4w..4w+3.
// Phase B: wave w = (rh=w>>2, js=w&3) -> rows rh*16..+15, j-slice js*64..+63.
__global__ __launch_bounds__(512) void gat_main(
    const int* __restrict__ adj, const float* __restrict__ wh1s,
    const float* __restrict__ wh2s, const unsigned short* __restrict__ whbp,
    float* __restrict__ out)
{
    __shared__ __align__(16) char smem[2 * BM * RJ * 2];  // 32 KB P dbuf / sAcc alias
    __shared__ float sRow[BM];

    const int tid = threadIdx.x, lane = tid & 63, wid = tid >> 6;
    const int rb = blockIdx.x;
    const int r16 = lane & 15, klo = lane >> 4;

    // phase-A role: 4 rows per wave
    const int ra0 = 4 * wid;
    const int* adjr[4];
    float wh1v[4];
    int xw[4];
    #pragma unroll
    for (int r = 0; r < 4; ++r) {
        const int grow = rb * BM + ra0 + r;
        adjr[r] = adj + (size_t)grow * NN;
        wh1v[r] = wh1s[grow];
        xw[r]   = ((ra0 + r) & 7) << 4;
    }

    // phase-B role
    const int rh = wid >> 2, js = wid & 3;
    const int rloc = rh * 16 + r16;
    const int xr = (rloc & 7) << 4;

    f32x4 acc[4];
    #pragma unroll
    for (int nb = 0; nb < 4; ++nb) acc[nb] = (f32x4){0.f, 0.f, 0.f, 0.f};
    float rs[4] = {0.f, 0.f, 0.f, 0.f};

    struct AdjSet { i32x4 a[4]; f32x4 w; };
    AdjSet S0, S1;
    bf16x8 B0[8], B1[8];   // B frag double-buffer in registers (static idx only)

    auto LOADA = [&](AdjSet& S, int rr) {
        const int jb = rr * RJ + lane * 4;
        #pragma unroll
        for (int r = 0; r < 4; ++r)
            S.a[r] = *(const i32x4*)(adjr[r] + jb);
        S.w = *(const f32x4*)(wh2s + jb);
    };

    // load this wave's B frags for round rr straight to registers
    auto BLOADG = [&](bf16x8* B, int rr) {
        #pragma unroll
        for (int kk = 0; kk < 2; ++kk) {
            const unsigned short* bp =
                whbp + (size_t)(rr * 8 + js * 2 + kk) * 2048 + lane * 8;
            #pragma unroll
            for (int nb = 0; nb < 4; ++nb)
                B[kk * 4 + nb] = *(const bf16x8*)(bp + nb * 512);
        }
    };

    auto PROC = [&](i32x4 ad, f32x4 w2, float w1, float& rsum) -> bf16x4 {
        bf16x4 o;
        #pragma unroll
        for (int u = 0; u < 4; ++u) {
            float tt = w1 + w2[u];
            float e  = fmaxf(tt, 0.2f * tt);             // leaky (log2 domain)
            float p  = (ad[u] > 0) ? __builtin_amdgcn_exp2f(e) : 0.f;
            rsum += p;
            o[u] = (__bf16)p;
        }
        return o;
    };

    auto STORE = [&](int rr, AdjSet& S) {   // produce P(rr) into P half rr&1
        char* Pb = smem + ((rr & 1) << 14);
        #pragma unroll
        for (int r = 0; r < 4; ++r) {
            bf16x4 p = PROC(S.a[r], S.w, wh1v[r], rs[r]);
            *(bf16x4*)(Pb + (ra0 + r) * 512 + ((lane * 8) ^ xw[r])) = p;
        }
    };

    // PHASE(rr): bar -> BLOADG(rr+1 into Bnext) -> STORE(rr+1) -> LOADA(rr+3)
    //            -> MFMA(rr) [P from LDS, B from Bcur regs, counted vmcnt]
    auto PHASE = [&](int rr, AdjSet& Scons, bf16x8* Bcur, bf16x8* Bnext) {
        bar_lgkm_only();                 // P(rr) visible; VMEM stays in flight

        if (rr + 1 < NR) {
            BLOADG(Bnext, rr + 1);
            STORE(rr + 1, Scons);
            if (rr + 3 < NR) LOADA(Scons, rr + 3);
        }

        const char* Pb = smem + ((rr & 1) << 14);
        #pragma unroll
        for (int kk = 0; kk < 2; ++kk) {
            bf16x8 af = *(const bf16x8*)(Pb + rloc * 512 +
                ((js * 128 + kk * 64 + klo * 16) ^ xr));
            #pragma unroll
            for (int nb = 0; nb < 4; ++nb)
                acc[nb] = __builtin_amdgcn_mfma_f32_16x16x32_bf16(
                    af, Bcur[kk * 4 + nb], acc[nb], 0, 0, 0);
        }
    };

    // prologue: adj depth-2, B(0) in regs, P(0) in LDS
    LOADA(S0, 0);
    LOADA(S1, 1);
    BLOADG(B0, 0);
    STORE(0, S0);
    LOADA(S0, 2);

    for (int rr = 0; rr < NR; rr += 2) {
        PHASE(rr,     S1, B0, B1);   // consume B(rr),   load B(rr+1)
        PHASE(rr + 1, S0, B1, B0);   // consume B(rr+1), load B(rr+2)
    }

    // per-row softmax denominators
    #pragma unroll
    for (int r = 0; r < 4; ++r) {
        float v = rs[r];
        #pragma unroll
        for (int off = 32; off; off >>= 1) v += __shfl_xor(v, off);
        if (lane == 0) sRow[ra0 + r] = v;
    }

    __syncthreads();   // cold: full drain fine; safe to alias smem as sAcc

    // spill acc (C/D layout: row = klo*4 + q, col = nb*16 + r16)
    float* sAcc = (float*)smem;          // [8][1024] = 32 KB (P region)
    #pragma unroll
    for (int nb = 0; nb < 4; ++nb) {
        #pragma unroll
        for (int q = 0; q < 4; ++q) {
            int lrow = klo * 4 + q;
            sAcc[wid * 1024 + lrow * 64 + nb * 16 + r16] = acc[nb][q];
        }
    }
    __syncthreads();

    // combine the 4 j-slice waves per rowhalf, divide, write out
    for (int idx = tid; idx < BM * OUTF; idx += 512) {
        int row = idx >> 6, c = idx & 63, rhh = row >> 4;
        float s = 0.f;
        #pragma unroll
        for (int j4 = 0; j4 < 4; ++j4)
            s += sAcc[(rhh * 4 + j4) * 1024 + (row & 15) * 64 + c];
        out[(size_t)(rb * BM + row) * OUTF + c] = s / sRow[row];
    }
}

extern "C" void kernel_launch(void* const* d_in, const int* in_sizes, int n_in,
                              void* d_out, int out_size, void* d_ws, size_t ws_size,
                              hipStream_t stream) {
    const float* h   = (const float*)d_in[0];
    const float* W   = (const float*)d_in[1];
    const float* a   = (const float*)d_in[2];
    const int*   adj = (const int*)d_in[3];
    float* out = (float*)d_out;

    char* ws = (char*)d_ws;
    unsigned short* whbp = (unsigned short*)ws;             // 1 MB
    float* wh1s = (float*)(ws + (1u << 20));                // 32 KB
    float* wh2s = (float*)(ws + (1u << 20) + 32768);        // 32 KB

    gat_prep<<<NN / BM, 512, 0, stream>>>(h, W, a, wh1s, wh2s, whbp);
    gat_main<<<NN / BM, 512, 0, stream>>>(adj, wh1s, wh2s, whbp, out);
}

// Round 19
// 68.619 us; speedup vs baseline: 2.3931x; 1.0076x over previous
//
#include <hip/hip_runtime.h>

// GAT layer, N=8192, IN_F=128, OUT_F=64.
//   Wh = h@W; Wh1 = Wh@a1; Wh2 = Wh@a2
//   e[i][j] = leakyrelu(Wh1[i]+Wh2[j]); p = adj>0 ? exp(e) : 0
//   out = (P @ Wh) / rowsum(P)
// Round 18: single change vs round 15 (71.2us best) — B fragments staged
// into REGISTERS one full phase ahead (2 named sets, static idx), not LDS.
// Removes the B LDS round-trip (the bulk of 590K conflict-cycles/rep and
// of the barrier's lgkm drain), LDS drops 96KB->32KB. adj stays depth-2
// counted-vmcnt; P staging via swizzled LDS unchanged.

#define NN    8192
#define INF   128
#define OUTF  64
#define BM    32       // rows per block
#define RJ    256      // j per round
#define NR    (NN/RJ)  // 32 rounds
#define LOG2E 1.4426950408889634f

typedef float  f32x4 __attribute__((ext_vector_type(4)));
typedef int    i32x4 __attribute__((ext_vector_type(4)));
typedef __bf16 bf16x4 __attribute__((ext_vector_type(4)));
typedef __bf16 bf16x8 __attribute__((ext_vector_type(8)));

__device__ __forceinline__ unsigned short f2bf(float x) {
    unsigned u = __builtin_bit_cast(unsigned, x);
    return (unsigned short)((u + 0x7fffu + ((u >> 16) & 1u)) >> 16);
}

// Raw barrier: own LDS ops drained (lgkmcnt(0)), VMEM left in flight.
__device__ __forceinline__ void bar_lgkm_only() {
    asm volatile("s_waitcnt lgkmcnt(0)" ::: "memory");
    __builtin_amdgcn_sched_barrier(0);
    __builtin_amdgcn_s_barrier();
    __builtin_amdgcn_sched_barrier(0);
}

// ---------------- kernel 1: Wh, scaled Wh1/Wh2, packed bf16 Wh (B-frag order)
// (byte-identical to round 6)
__global__ __launch_bounds__(512) void gat_prep(
    const float* __restrict__ h, const float* __restrict__ W,
    const float* __restrict__ a, float* __restrict__ wh1s,
    float* __restrict__ wh2s, unsigned short* __restrict__ whbp)
{
    __shared__ float sWt[64 * 132];   // W transposed [col][k], padded
    __shared__ float sWh[32][64];
    __shared__ float sH[8][128];
    __shared__ float sA[2 * OUTF];
    const int tid = threadIdx.x, lane = tid & 63, wid = tid >> 6;
    const int rb = blockIdx.x;

    for (int idx = tid; idx < INF * OUTF; idx += 512) {
        int k = idx >> 6, c = idx & 63;
        sWt[c * 132 + k] = W[idx];
    }
    if (tid < 2 * OUTF) sA[tid] = a[tid];
    __syncthreads();

    #pragma unroll
    for (int i = 0; i < 4; ++i) {
        const int row = wid * 4 + i;
        const int grow = rb * BM + row;
        sH[wid][lane]      = h[(size_t)grow * INF + lane];
        sH[wid][64 + lane] = h[(size_t)grow * INF + 64 + lane];
        float a0 = 0.f, a1 = 0.f, a2 = 0.f, a3 = 0.f;
        #pragma unroll
        for (int k = 0; k < INF; k += 4) {
            f32x4 wv = *(const f32x4*)(&sWt[lane * 132 + k]);
            f32x4 hv = *(const f32x4*)(&sH[wid][k]);
            a0 = fmaf(hv[0], wv[0], a0);
            a1 = fmaf(hv[1], wv[1], a1);
            a2 = fmaf(hv[2], wv[2], a2);
            a3 = fmaf(hv[3], wv[3], a3);
        }
        float acc = (a0 + a1) + (a2 + a3);
        float v1 = acc * sA[lane];
        float v2 = acc * sA[64 + lane];
        #pragma unroll
        for (int off = 32; off; off >>= 1) {
            v1 += __shfl_xor(v1, off);
            v2 += __shfl_xor(v2, off);
        }
        if (lane == 0) { wh1s[grow] = v1 * LOG2E; wh2s[grow] = v2 * LOG2E; }
        sWh[row][lane] = acc;
    }
    __syncthreads();

    // coalesced whbp chunk write: thread t -> shorts t*4 .. t*4+3
    {
        const int t = tid;
        const int nb  = t >> 7;
        const int lp  = (t & 127) >> 1;
        const int jj0 = (t & 1) * 4;
        const int col = nb * 16 + (lp & 15);
        const int jb  = (lp >> 4) * 8 + jj0;
        unsigned short v[4];
        #pragma unroll
        for (int q = 0; q < 4; ++q) v[q] = f2bf(sWh[jb + q][col]);
        *(uint2*)(whbp + (size_t)rb * 2048 + t * 4) = *(const uint2*)v;
    }
}

// ---------------- kernel 2: P via swizzled LDS, B via register double-buffer
// 256 blocks x 512 threads (8 waves). Phase A: wave w owns rows 4w..4w+3.
// Phase B: wave w = (rh=w>>2, js=w&3) -> rows rh*16..+15, j-slice js*64..+63.
__global__ __launch_bounds__(512) void gat_main(
    const int* __restrict__ adj, const float* __restrict__ wh1s,
    const float* __restrict__ wh2s, const unsigned short* __restrict__ whbp,
    float* __restrict__ out)
{
    __shared__ __align__(16) char smem[2 * BM * RJ * 2];  // 32 KB P dbuf / sAcc alias
    __shared__ float sRow[BM];

    const int tid = threadIdx.x, lane = tid & 63, wid = tid >> 6;
    const int rb = blockIdx.x;
    const int r16 = lane & 15, klo = lane >> 4;

    // phase-A role: 4 rows per wave
    const int ra0 = 4 * wid;
    const int* adjr[4];
    float wh1v[4];
    int xw[4];
    #pragma unroll
    for (int r = 0; r < 4; ++r) {
        const int grow = rb * BM + ra0 + r;
        adjr[r] = adj + (size_t)grow * NN;
        wh1v[r] = wh1s[grow];
        xw[r]   = ((ra0 + r) & 7) << 4;
    }

    // phase-B role
    const int rh = wid >> 2, js = wid & 3;
    const int rloc = rh * 16 + r16;
    const int xr = (rloc & 7) << 4;

    f32x4 acc[4];
    #pragma unroll
    for (int nb = 0; nb < 4; ++nb) acc[nb] = (f32x4){0.f, 0.f, 0.f, 0.f};
    float rs[4] = {0.f, 0.f, 0.f, 0.f};

    struct AdjSet { i32x4 a[4]; f32x4 w; };
    AdjSet S0, S1;
    bf16x8 B0[8], B1[8];   // B frag double-buffer in registers (static idx only)

    auto LOADA = [&](AdjSet& S, int rr) {
        const int jb = rr * RJ + lane * 4;
        #pragma unroll
        for (int r = 0; r < 4; ++r)
            S.a[r] = *(const i32x4*)(adjr[r] + jb);
        S.w = *(const f32x4*)(wh2s + jb);
    };

    // load this wave's B frags for round rr straight to registers
    auto BLOADG = [&](bf16x8* B, int rr) {
        #pragma unroll
        for (int kk = 0; kk < 2; ++kk) {
            const unsigned short* bp =
                whbp + (size_t)(rr * 8 + js * 2 + kk) * 2048 + lane * 8;
            #pragma unroll
            for (int nb = 0; nb < 4; ++nb)
                B[kk * 4 + nb] = *(const bf16x8*)(bp + nb * 512);
        }
    };

    auto PROC = [&](i32x4 ad, f32x4 w2, float w1, float& rsum) -> bf16x4 {
        bf16x4 o;
        #pragma unroll
        for (int u = 0; u < 4; ++u) {
            float tt = w1 + w2[u];
            float e  = fmaxf(tt, 0.2f * tt);             // leaky (log2 domain)
            float p  = (ad[u] > 0) ? __builtin_amdgcn_exp2f(e) : 0.f;
            rsum += p;
            o[u] = (__bf16)p;
        }
        return o;
    };

    auto STORE = [&](int rr, AdjSet& S) {   // produce P(rr) into P half rr&1
        char* Pb = smem + ((rr & 1) << 14);
        #pragma unroll
        for (int r = 0; r < 4; ++r) {
            bf16x4 p = PROC(S.a[r], S.w, wh1v[r], rs[r]);
            *(bf16x4*)(Pb + (ra0 + r) * 512 + ((lane * 8) ^ xw[r])) = p;
        }
    };

    // PHASE(rr): bar -> BLOADG(rr+1 into Bnext) -> STORE(rr+1) -> LOADA(rr+3)
    //            -> MFMA(rr) [P from LDS, B from Bcur regs, counted vmcnt]
    auto PHASE = [&](int rr, AdjSet& Scons, bf16x8* Bcur, bf16x8* Bnext) {
        bar_lgkm_only();                 // P(rr) visible; VMEM stays in flight

        if (rr + 1 < NR) {
            BLOADG(Bnext, rr + 1);
            STORE(rr + 1, Scons);
            if (rr + 3 < NR) LOADA(Scons, rr + 3);
        }

        const char* Pb = smem + ((rr & 1) << 14);
        #pragma unroll
        for (int kk = 0; kk < 2; ++kk) {
            bf16x8 af = *(const bf16x8*)(Pb + rloc * 512 +
                ((js * 128 + kk * 64 + klo * 16) ^ xr));
            #pragma unroll
            for (int nb = 0; nb < 4; ++nb)
                acc[nb] = __builtin_amdgcn_mfma_f32_16x16x32_bf16(
                    af, Bcur[kk * 4 + nb], acc[nb], 0, 0, 0);
        }
    };

    // prologue: adj depth-2, B(0) in regs, P(0) in LDS
    LOADA(S0, 0);
    LOADA(S1, 1);
    BLOADG(B0, 0);
    STORE(0, S0);
    LOADA(S0, 2);

    for (int rr = 0; rr < NR; rr += 2) {
        PHASE(rr,     S1, B0, B1);   // consume B(rr),   load B(rr+1)
        PHASE(rr + 1, S0, B1, B0);   // consume B(rr+1), load B(rr+2)
    }

    // per-row softmax denominators
    #pragma unroll
    for (int r = 0; r < 4; ++r) {
        float v = rs[r];
        #pragma unroll
        for (int off = 32; off; off >>= 1) v += __shfl_xor(v, off);
        if (lane == 0) sRow[ra0 + r] = v;
    }

    __syncthreads();   // cold: full drain fine; safe to alias smem as sAcc

    // spill acc (C/D layout: row = klo*4 + q, col = nb*16 + r16)
    float* sAcc = (float*)smem;          // [8][1024] = 32 KB (P region)
    #pragma unroll
    for (int nb = 0; nb < 4; ++nb) {
        #pragma unroll
        for (int q = 0; q < 4; ++q) {
            int lrow = klo * 4 + q;
            sAcc[wid * 1024 + lrow * 64 + nb * 16 + r16] = acc[nb][q];
        }
    }
    __syncthreads();

    // combine the 4 j-slice waves per rowhalf, divide, write out
    for (int idx = tid; idx < BM * OUTF; idx += 512) {
        int row = idx >> 6, c = idx & 63, rhh = row >> 4;
        float s = 0.f;
        #pragma unroll
        for (int j4 = 0; j4 < 4; ++j4)
            s += sAcc[(rhh * 4 + j4) * 1024 + (row & 15) * 64 + c];
        out[(size_t)(rb * BM + row) * OUTF + c] = s / sRow[row];
    }
}

extern "C" void kernel_launch(void* const* d_in, const int* in_sizes, int n_in,
                              void* d_out, int out_size, void* d_ws, size_t ws_size,
                              hipStream_t stream) {
    const float* h   = (const float*)d_in[0];
    const float* W   = (const float*)d_in[1];
    const float* a   = (const float*)d_in[2];
    const int*   adj = (const int*)d_in[3];
    float* out = (float*)d_out;

    char* ws = (char*)d_ws;
    unsigned short* whbp = (unsigned short*)ws;             // 1 MB
    float* wh1s = (float*)(ws + (1u << 20));                // 32 KB
    float* wh2s = (float*)(ws + (1u << 20) + 32768);        // 32 KB

    gat_prep<<<NN / BM, 512, 0, stream>>>(h, W, a, wh1s, wh2s, whbp);
    gat_main<<<NN / BM, 512, 0, stream>>>(adj, wh1s, wh2s, whbp, out);
}